// Round 2
// 1264.837 us; speedup vs baseline: 1.0991x; 1.0991x over previous
//
#include <hip/hip_runtime.h>
#include <stdint.h>

#define B_ 64
#define D_ 1024
#define H_ 1024
#define V_ 32000
#define T_ 20
#define SOS_ 0

typedef __attribute__((ext_vector_type(8))) __bf16 bf16x8;
typedef __attribute__((ext_vector_type(4))) float f32x4;

// ---------------------------------------------------------------- helpers
__device__ __forceinline__ uint32_t ord_of_float(float x) {
    uint32_t u = __float_as_uint(x);
    return (u & 0x80000000u) ? ~u : (u | 0x80000000u);
}

__device__ __forceinline__ unsigned long long shfl_xor_u64(unsigned long long x, int m) {
    return (unsigned long long)__shfl_xor((long long)x, m, 64);
}

// round-to-nearest-even fp32 -> bf16 split: f ~= hi + lo (each bf16)
__device__ __forceinline__ void split_bf16(float f, unsigned short* hi, unsigned short* lo) {
    uint32_t u = __float_as_uint(f);
    uint32_t rh = (u + 0x7FFFu + ((u >> 16) & 1u)) >> 16;
    *hi = (unsigned short)rh;
    float fl = f - __uint_as_float(rh << 16);
    uint32_t ul = __float_as_uint(fl);
    uint32_t rl = (ul + 0x7FFFu + ((ul >> 16) & 1u)) >> 16;
    *lo = (unsigned short)rl;
}

// async global -> LDS, 16 B per lane (dest is wave-uniform base + lane*16)
__device__ __forceinline__ void gload_lds16(const void* g, void* l) {
    __builtin_amdgcn_global_load_lds(
        (const __attribute__((address_space(1))) void*)g,
        (__attribute__((address_space(3))) void*)l, 16, 0, 0);
}

// ---------------------------------------------------------------- weight split
__global__ __launch_bounds__(256) void k_split_w(const float* __restrict__ src,
    unsigned short* __restrict__ hi, unsigned short* __restrict__ lo, int n4)
{
    int i = blockIdx.x * 256 + threadIdx.x;
    if (i >= n4) return;
    float4 v = ((const float4*)src)[i];
    ushort4 h, l;
    split_bf16(v.x, &h.x, &l.x);
    split_bf16(v.y, &h.y, &l.y);
    split_bf16(v.z, &h.z, &l.z);
    split_bf16(v.w, &h.w, &l.w);
    ((ushort4*)hi)[i] = h;
    ((ushort4*)lo)[i] = l;
}

// ---------------------------------------------------------------- init hidden
// h0[b][j] = dot(latent[b,:], Wp[j,:]) + bp[j].  One wave per output.
__global__ __launch_bounds__(256) void k_init_hidden(
    const float* __restrict__ latent, const float* __restrict__ Wp,
    const float* __restrict__ bp, float* __restrict__ h0,
    unsigned short* __restrict__ hhi, unsigned short* __restrict__ hlo)
{
    int gw = (blockIdx.x * 256 + threadIdx.x) >> 6;  // global wave id
    int lane = threadIdx.x & 63;
    int j = gw >> 6;
    int b = gw & 63;
    const float4* a4 = (const float4*)(latent + b * D_);
    const float4* w4 = (const float4*)(Wp + (size_t)j * D_);
    float s = 0.f;
#pragma unroll
    for (int i = 0; i < 4; i++) {
        float4 a = a4[lane + 64 * i];
        float4 w = w4[lane + 64 * i];
        s += a.x * w.x + a.y * w.y + a.z * w.z + a.w * w.w;
    }
#pragma unroll
    for (int off = 32; off; off >>= 1) s += __shfl_down(s, off, 64);
    if (lane == 0) {
        float v = s + bp[j];
        h0[b * H_ + j] = v;
        unsigned short h_, l_;
        split_bf16(v, &h_, &l_);
        hhi[b * H_ + j] = h_;
        hlo[b * H_ + j] = l_;
    }
}

// ---------------------------------------------------------------- x prep (SOS)
__global__ __launch_bounds__(256) void k_prep_x0(const float* __restrict__ emb,
    unsigned short* __restrict__ xhi, unsigned short* __restrict__ xlo)
{
    int b = blockIdx.x;
    int tid = threadIdx.x;
    float4 v4 = *(const float4*)(emb + (size_t)SOS_ * H_ + tid * 4);
    ushort4 h, l;
    split_bf16(v4.x, &h.x, &l.x);
    split_bf16(v4.y, &h.y, &l.y);
    split_bf16(v4.z, &h.z, &l.z);
    split_bf16(v4.w, &h.w, &l.w);
    *(ushort4*)(xhi + (size_t)b * H_ + tid * 4) = h;
    *(ushort4*)(xlo + (size_t)b * H_ + tid * 4) = l;
}

// ---------------------------------------------------------------- gates GEMM (MFMA)
// gi = x@Wih^T, gh = h@Whh^T as split-K fp32 partials.  Grid 192: jt(48) x half(2) x ks(2).
// B (weights) staged hi/lo bf16 via global_load_lds (XOR-swizzled src, swizzled read).
// A (x or h) split planes read directly from global (L2-resident, 256 KB).
__global__ __launch_bounds__(256) void k_gates_gemm2(
    const unsigned short* __restrict__ xhi, const unsigned short* __restrict__ xlo,
    const unsigned short* __restrict__ hhi, const unsigned short* __restrict__ hlo,
    const unsigned short* __restrict__ wihh, const unsigned short* __restrict__ wihl,
    const unsigned short* __restrict__ whhh, const unsigned short* __restrict__ whhl,
    float* __restrict__ gbuf)
{
    __shared__ __align__(128) char Bsm[2][16384];  // [buf][hi 8K | lo 8K]
    int tid = threadIdx.x;
    int lane = tid & 63;
    int wv = tid >> 6;
    int blk = blockIdx.x;
    int jt = blk % 48;
    int rest = blk / 48;
    int half = rest & 1;        // 0: ih (A=x), 1: hh (A=h)
    int ks = rest >> 1;
    int kbase = ks * 512;
    int row0 = jt * 64;

    const unsigned short* Ahi_g = half ? hhi : xhi;
    const unsigned short* Alo_g = half ? hlo : xlo;
    const unsigned short* Bhi_g = half ? whhh : wihh;
    const unsigned short* Blo_g = half ? whhl : wihl;

    // staging geometry: round rr covers rows rr*32..rr*32+31; lane -> (row, 16B slot)
    int r0 = wv * 8 + (lane >> 3);          // tile row, round 0
    int r1 = r0 + 32;                       // tile row, round 1
    int kslt = (lane & 7) * 16;             // byte slot within 128 B row
    size_t so0 = (size_t)(row0 + r0) * 2048 + (size_t)(kslt ^ ((r0 & 7) << 4));
    size_t so1 = (size_t)(row0 + r1) * 2048 + (size_t)(kslt ^ ((r1 & 7) << 4));

    int mrow = wv * 16 + (lane & 15);
    int koff = (lane >> 4) * 8;             // elements
    int kb = koff * 2;                      // bytes {0,16,32,48}

    f32x4 acc[4];
#pragma unroll
    for (int i = 0; i < 4; i++) acc[i] = (f32x4){0.f, 0.f, 0.f, 0.f};

    auto stage = [&](int BUF, int KC) {
        const char* bh = (const char*)Bhi_g + (size_t)KC * 2;
        const char* bl = (const char*)Blo_g + (size_t)KC * 2;
        char* base = Bsm[BUF] + wv * 1024;  // wave-uniform; HW adds lane*16
        gload_lds16(bh + so0, base);
        gload_lds16(bh + so1, base + 4096);
        gload_lds16(bl + so0, base + 8192);
        gload_lds16(bl + so1, base + 12288);
    };

    int buf = 0;
    stage(0, kbase);
    __syncthreads();
    for (int it = 0; it < 8; ++it) {
        int kc = kbase + it * 64;
        if (it < 7) stage(buf ^ 1, kc + 64);
        const unsigned short* ap = Ahi_g + (size_t)mrow * 1024 + kc + koff;
        const unsigned short* alp = Alo_g + (size_t)mrow * 1024 + kc + koff;
        bf16x8 ah0 = *(const bf16x8*)ap;
        bf16x8 ah1 = *(const bf16x8*)(ap + 32);
        bf16x8 al0 = *(const bf16x8*)alp;
        bf16x8 al1 = *(const bf16x8*)(alp + 32);
        const char* bhp = Bsm[buf];
        const char* blp = Bsm[buf] + 8192;
#pragma unroll
        for (int tv = 0; tv < 4; tv++) {
            int brow = tv * 16 + (lane & 15);
            int swz = (brow & 7) << 4;
            int ro = brow * 128;
            bf16x8 bh0 = *(const bf16x8*)(bhp + ro + (kb ^ swz));
            bf16x8 bh1 = *(const bf16x8*)(bhp + ro + ((kb + 64) ^ swz));
            bf16x8 bl0 = *(const bf16x8*)(blp + ro + (kb ^ swz));
            bf16x8 bl1 = *(const bf16x8*)(blp + ro + ((kb + 64) ^ swz));
            acc[tv] = __builtin_amdgcn_mfma_f32_16x16x32_bf16(ah0, bh0, acc[tv], 0, 0, 0);
            acc[tv] = __builtin_amdgcn_mfma_f32_16x16x32_bf16(ah1, bh1, acc[tv], 0, 0, 0);
            acc[tv] = __builtin_amdgcn_mfma_f32_16x16x32_bf16(al0, bh0, acc[tv], 0, 0, 0);
            acc[tv] = __builtin_amdgcn_mfma_f32_16x16x32_bf16(al1, bh1, acc[tv], 0, 0, 0);
            acc[tv] = __builtin_amdgcn_mfma_f32_16x16x32_bf16(ah0, bl0, acc[tv], 0, 0, 0);
            acc[tv] = __builtin_amdgcn_mfma_f32_16x16x32_bf16(ah1, bl1, acc[tv], 0, 0, 0);
        }
        __syncthreads();   // drains vmcnt (stage done) + all waves done reading buf
        buf ^= 1;
    }

    // epilogue: C/D layout col = lane&15 (n), row = (lane>>4)*4 + reg (b)
    int col = lane & 15;
    int quad = lane >> 4;
    float* og = gbuf + (size_t)((ks * 2 + half) * 64) * 3072;
#pragma unroll
    for (int tv = 0; tv < 4; tv++) {
#pragma unroll
        for (int r = 0; r < 4; r++) {
            int b = wv * 16 + quad * 4 + r;
            og[(size_t)b * 3072 + jt * 64 + tv * 16 + col] = acc[tv][r];
        }
    }
}

// ---------------------------------------------------------------- gate elementwise
__global__ __launch_bounds__(256) void k_gru_elem2(
    const float* __restrict__ gbuf, const float* __restrict__ bih,
    const float* __restrict__ bhh, const float* __restrict__ hprev,
    float* __restrict__ hnext, unsigned short* __restrict__ hnhi,
    unsigned short* __restrict__ hnlo)
{
    int idx = blockIdx.x * 256 + threadIdx.x;   // 0..65535
    int b = idx >> 10;
    int j = idx & 1023;
    const float* g00 = gbuf + (size_t)b * 3072;
    const float* g01 = gbuf + (size_t)(64 + b) * 3072;
    const float* g10 = gbuf + (size_t)(128 + b) * 3072;
    const float* g11 = gbuf + (size_t)(192 + b) * 3072;
    float ir = g00[j] + g10[j] + bih[j];
    float hr = g01[j] + g11[j] + bhh[j];
    float iz = g00[H_ + j] + g10[H_ + j] + bih[H_ + j];
    float hz = g01[H_ + j] + g11[H_ + j] + bhh[H_ + j];
    float in_ = g00[2 * H_ + j] + g10[2 * H_ + j] + bih[2 * H_ + j];
    float hn = g01[2 * H_ + j] + g11[2 * H_ + j] + bhh[2 * H_ + j];
    float r = 1.f / (1.f + expf(-(ir + hr)));
    float z = 1.f / (1.f + expf(-(iz + hz)));
    float n = tanhf(in_ + r * hn);
    float hp = hprev[idx];
    float v = (1.f - z) * n + z * hp;
    hnext[idx] = v;
    unsigned short h_, l_;
    split_bf16(v, &h_, &l_);
    hnhi[idx] = h_;
    hnlo[idx] = l_;
}

// ---------------------------------------------------------------- logits + argmax
// logits = h @ Wout^T + bout via split-bf16 MFMA.  Block: 64 b x 64 v.
// Wout hi/lo planes staged via global_load_lds (swizzled); h planes direct from L2.
__global__ __launch_bounds__(256) void k_logits_argmax2(
    const unsigned short* __restrict__ hhi, const unsigned short* __restrict__ hlo,
    const unsigned short* __restrict__ wouth, const unsigned short* __restrict__ woutl,
    const float* __restrict__ bout, unsigned long long* __restrict__ partials,
    int nblk)
{
    __shared__ __align__(128) char Bsm[2][16384];
    int tid = threadIdx.x;
    int lane = tid & 63;
    int wv = tid >> 6;
    int row0 = blockIdx.x * 64;   // vbase

    int r0 = wv * 8 + (lane >> 3);
    int r1 = r0 + 32;
    int kslt = (lane & 7) * 16;
    size_t so0 = (size_t)(row0 + r0) * 2048 + (size_t)(kslt ^ ((r0 & 7) << 4));
    size_t so1 = (size_t)(row0 + r1) * 2048 + (size_t)(kslt ^ ((r1 & 7) << 4));

    int mrow = wv * 16 + (lane & 15);
    int koff = (lane >> 4) * 8;
    int kb = koff * 2;

    f32x4 acc[4];
#pragma unroll
    for (int i = 0; i < 4; i++) acc[i] = (f32x4){0.f, 0.f, 0.f, 0.f};

    auto stage = [&](int BUF, int KC) {
        const char* bh = (const char*)wouth + (size_t)KC * 2;
        const char* bl = (const char*)woutl + (size_t)KC * 2;
        char* base = Bsm[BUF] + wv * 1024;
        gload_lds16(bh + so0, base);
        gload_lds16(bh + so1, base + 4096);
        gload_lds16(bl + so0, base + 8192);
        gload_lds16(bl + so1, base + 12288);
    };

    int buf = 0;
    stage(0, 0);
    __syncthreads();
    for (int it = 0; it < 16; ++it) {
        int kc = it * 64;
        if (it < 15) stage(buf ^ 1, kc + 64);
        const unsigned short* ap = hhi + (size_t)mrow * 1024 + kc + koff;
        const unsigned short* alp = hlo + (size_t)mrow * 1024 + kc + koff;
        bf16x8 ah0 = *(const bf16x8*)ap;
        bf16x8 ah1 = *(const bf16x8*)(ap + 32);
        bf16x8 al0 = *(const bf16x8*)alp;
        bf16x8 al1 = *(const bf16x8*)(alp + 32);
        const char* bhp = Bsm[buf];
        const char* blp = Bsm[buf] + 8192;
#pragma unroll
        for (int tv = 0; tv < 4; tv++) {
            int brow = tv * 16 + (lane & 15);
            int swz = (brow & 7) << 4;
            int ro = brow * 128;
            bf16x8 bh0 = *(const bf16x8*)(bhp + ro + (kb ^ swz));
            bf16x8 bh1 = *(const bf16x8*)(bhp + ro + ((kb + 64) ^ swz));
            bf16x8 bl0 = *(const bf16x8*)(blp + ro + (kb ^ swz));
            bf16x8 bl1 = *(const bf16x8*)(blp + ro + ((kb + 64) ^ swz));
            acc[tv] = __builtin_amdgcn_mfma_f32_16x16x32_bf16(ah0, bh0, acc[tv], 0, 0, 0);
            acc[tv] = __builtin_amdgcn_mfma_f32_16x16x32_bf16(ah1, bh1, acc[tv], 0, 0, 0);
            acc[tv] = __builtin_amdgcn_mfma_f32_16x16x32_bf16(al0, bh0, acc[tv], 0, 0, 0);
            acc[tv] = __builtin_amdgcn_mfma_f32_16x16x32_bf16(al1, bh1, acc[tv], 0, 0, 0);
            acc[tv] = __builtin_amdgcn_mfma_f32_16x16x32_bf16(ah0, bl0, acc[tv], 0, 0, 0);
            acc[tv] = __builtin_amdgcn_mfma_f32_16x16x32_bf16(ah1, bl1, acc[tv], 0, 0, 0);
        }
        __syncthreads();
        buf ^= 1;
    }

    // epilogue: argmax keys.  C/D layout col = lane&15 (v), row = (lane>>4)*4 + reg (b)
    int col = lane & 15;
    int quad = lane >> 4;
    unsigned long long kmax[4] = {0ull, 0ull, 0ull, 0ull};
#pragma unroll
    for (int tv = 0; tv < 4; tv++) {
        int v = row0 + tv * 16 + col;
        float bo = bout[v];
#pragma unroll
        for (int r = 0; r < 4; r++) {
            float lg = acc[tv][r] + bo;
            unsigned long long key = ((unsigned long long)ord_of_float(lg) << 32)
                                   | (unsigned long long)(0x7FFFFFFFu - (uint32_t)v);
            if (key > kmax[r]) kmax[r] = key;
        }
    }
#pragma unroll
    for (int r = 0; r < 4; r++) {
        unsigned long long k = kmax[r];
#pragma unroll
        for (int off = 1; off < 16; off <<= 1) {
            unsigned long long o = shfl_xor_u64(k, off);
            if (o > k) k = o;
        }
        kmax[r] = k;
    }
    if (col == 0) {
#pragma unroll
        for (int r = 0; r < 4; r++) {
            int b = wv * 16 + quad * 4 + r;
            partials[(size_t)b * nblk + blockIdx.x] = kmax[r];
        }
    }
}

// ---------------------------------------------------------------- token reduce + next-x prep
__global__ __launch_bounds__(256) void k_token2(
    const unsigned long long* __restrict__ partials, int nblk,
    int* __restrict__ tok, float* __restrict__ out_tokens, int t,
    const float* __restrict__ emb,
    unsigned short* __restrict__ xhi, unsigned short* __restrict__ xlo)
{
    __shared__ int s_tok;
    int b = blockIdx.x;
    int tid = threadIdx.x;
    if (tid < 64) {
        unsigned long long k = 0ull;
        for (int i = tid; i < nblk; i += 64) {
            unsigned long long p = partials[(size_t)b * nblk + i];
            if (p > k) k = p;
        }
#pragma unroll
        for (int off = 32; off; off >>= 1) {
            unsigned long long o = shfl_xor_u64(k, off);
            if (o > k) k = o;
        }
        if (tid == 0) {
            int v = (int)(0x7FFFFFFFu - (uint32_t)(k & 0xFFFFFFFFull));
            tok[b] = v;
            out_tokens[b * T_ + t] = (float)v;
            s_tok = v;
        }
    }
    __syncthreads();
    int row = s_tok;
    float4 v4 = *(const float4*)(emb + (size_t)row * H_ + tid * 4);
    ushort4 h, l;
    split_bf16(v4.x, &h.x, &l.x);
    split_bf16(v4.y, &h.y, &l.y);
    split_bf16(v4.z, &h.z, &l.z);
    split_bf16(v4.w, &h.w, &l.w);
    *(ushort4*)(xhi + (size_t)b * H_ + tid * 4) = h;
    *(ushort4*)(xlo + (size_t)b * H_ + tid * 4) = l;
}

// ---------------------------------------------------------------- final h copy
__global__ __launch_bounds__(256) void k_copy_h(const float* __restrict__ h,
                                               float* __restrict__ out)
{
    int i = (blockIdx.x * 256 + threadIdx.x) * 4;
    *(float4*)(out + i) = *(const float4*)(h + i);
}

// ---------------------------------------------------------------- launch
extern "C" void kernel_launch(void* const* d_in, const int* in_sizes, int n_in,
                              void* d_out, int out_size, void* d_ws, size_t ws_size,
                              hipStream_t stream)
{
    const float* latent = (const float*)d_in[0];
    const float* Wp     = (const float*)d_in[1];
    const float* bp     = (const float*)d_in[2];
    const float* emb    = (const float*)d_in[3];
    const float* Wih    = (const float*)d_in[4];
    const float* bih    = (const float*)d_in[5];
    const float* Whh    = (const float*)d_in[6];
    const float* bhh    = (const float*)d_in[7];
    const float* Wout   = (const float*)d_in[8];
    const float* bout   = (const float*)d_in[9];
    float* out = (float*)d_out;

    char* ws = (char*)d_ws;
    // ---- workspace layout (all offsets multiples of 1024) ----
    float* h0   = (float*)(ws + 0);             // 256 KiB
    float* h1   = (float*)(ws + 262144);        // 256 KiB
    int* tok    = (int*)(ws + 524288);          // 1 KiB
    unsigned long long* partials = (unsigned long long*)(ws + 525312);  // 256 KiB
    float* gbuf = (float*)(ws + 787456);        // 3 MiB
    unsigned short* hhi0 = (unsigned short*)(ws + 3933184);   // 128 KiB each
    unsigned short* hlo0 = (unsigned short*)(ws + 4064256);
    unsigned short* hhi1 = (unsigned short*)(ws + 4195328);
    unsigned short* hlo1 = (unsigned short*)(ws + 4326400);
    unsigned short* xhi  = (unsigned short*)(ws + 4457472);
    unsigned short* xlo  = (unsigned short*)(ws + 4588544);
    unsigned short* wihh = (unsigned short*)(ws + 4719616);   // 6 MiB each
    unsigned short* wihl = (unsigned short*)(ws + 11011072);
    unsigned short* whhh = (unsigned short*)(ws + 17302528);
    unsigned short* whhl = (unsigned short*)(ws + 23593984);
    unsigned short* wouth = (unsigned short*)(ws + 29885440); // 62.5 MiB each
    unsigned short* woutl = (unsigned short*)(ws + 95421440); // end 160957440

    const int NBLK = V_ / 64;   // 500

    // one-time weight splits (amortized over 20 steps)
    k_split_w<<<3072, 256, 0, stream>>>(Wih, wihh, wihl, 3 * H_ * H_ / 4);
    k_split_w<<<3072, 256, 0, stream>>>(Whh, whhh, whhl, 3 * H_ * H_ / 4);
    k_split_w<<<32000, 256, 0, stream>>>(Wout, wouth, woutl, V_ * H_ / 4);

    k_init_hidden<<<16384, 256, 0, stream>>>(latent, Wp, bp, h0, hhi0, hlo0);
    k_prep_x0<<<64, 256, 0, stream>>>(emb, xhi, xlo);

    float* hp = h0;  unsigned short* hphi = hhi0;  unsigned short* hplo = hlo0;
    float* hn = h1;  unsigned short* hnhi = hhi1;  unsigned short* hnlo = hlo1;
    for (int t = 0; t < T_; t++) {
        k_gates_gemm2<<<192, 256, 0, stream>>>(xhi, xlo, hphi, hplo,
                                               wihh, wihl, whhh, whhl, gbuf);
        k_gru_elem2<<<256, 256, 0, stream>>>(gbuf, bih, bhh, hp, hn, hnhi, hnlo);
        k_logits_argmax2<<<NBLK, 256, 0, stream>>>(hnhi, hnlo, wouth, woutl,
                                                   bout, partials, NBLK);
        k_token2<<<B_, 256, 0, stream>>>(partials, NBLK, tok, out, t, emb, xhi, xlo);
        { float* tf = hp; hp = hn; hn = tf; }
        { unsigned short* ts = hphi; hphi = hnhi; hnhi = ts; }
        { unsigned short* ts = hplo; hplo = hnlo; hnlo = ts; }
    }
    k_copy_h<<<64, 256, 0, stream>>>(hp, out + B_ * T_);
}

// Round 3
// 1170.648 us; speedup vs baseline: 1.1876x; 1.0805x over previous
//
#include <hip/hip_runtime.h>
#include <stdint.h>

#define B_ 64
#define D_ 1024
#define H_ 1024
#define V_ 32000
#define T_ 20
#define SOS_ 0

typedef __attribute__((ext_vector_type(8))) __bf16 bf16x8;
typedef __attribute__((ext_vector_type(4))) float f32x4;

// ---------------------------------------------------------------- helpers
__device__ __forceinline__ uint32_t ord_of_float(float x) {
    uint32_t u = __float_as_uint(x);
    return (u & 0x80000000u) ? ~u : (u | 0x80000000u);
}

__device__ __forceinline__ unsigned long long shfl_xor_u64(unsigned long long x, int m) {
    return (unsigned long long)__shfl_xor((long long)x, m, 64);
}

// round-to-nearest-even fp32 -> bf16 split: f ~= hi + lo (each bf16)
__device__ __forceinline__ void split_bf16(float f, unsigned short* hi, unsigned short* lo) {
    uint32_t u = __float_as_uint(f);
    uint32_t rh = (u + 0x7FFFu + ((u >> 16) & 1u)) >> 16;
    *hi = (unsigned short)rh;
    float fl = f - __uint_as_float(rh << 16);
    uint32_t ul = __float_as_uint(fl);
    uint32_t rl = (ul + 0x7FFFu + ((ul >> 16) & 1u)) >> 16;
    *lo = (unsigned short)rl;
}

// async global -> LDS, 16 B per lane (dest is wave-uniform base + lane*16)
__device__ __forceinline__ void gload_lds16(const void* g, void* l) {
    __builtin_amdgcn_global_load_lds(
        (const __attribute__((address_space(1))) void*)g,
        (__attribute__((address_space(3))) void*)l, 16, 0, 0);
}

// ---------------------------------------------------------------- weight split
__global__ __launch_bounds__(256) void k_split_w(const float* __restrict__ src,
    unsigned short* __restrict__ hi, unsigned short* __restrict__ lo, int n4)
{
    int i = blockIdx.x * 256 + threadIdx.x;
    if (i >= n4) return;
    float4 v = ((const float4*)src)[i];
    ushort4 h, l;
    split_bf16(v.x, &h.x, &l.x);
    split_bf16(v.y, &h.y, &l.y);
    split_bf16(v.z, &h.z, &l.z);
    split_bf16(v.w, &h.w, &l.w);
    ((ushort4*)hi)[i] = h;
    ((ushort4*)lo)[i] = l;
}

// ---------------------------------------------------------------- init hidden
__global__ __launch_bounds__(256) void k_init_hidden(
    const float* __restrict__ latent, const float* __restrict__ Wp,
    const float* __restrict__ bp, float* __restrict__ h0,
    unsigned short* __restrict__ hhi, unsigned short* __restrict__ hlo)
{
    int gw = (blockIdx.x * 256 + threadIdx.x) >> 6;  // global wave id
    int lane = threadIdx.x & 63;
    int j = gw >> 6;
    int b = gw & 63;
    const float4* a4 = (const float4*)(latent + b * D_);
    const float4* w4 = (const float4*)(Wp + (size_t)j * D_);
    float s = 0.f;
#pragma unroll
    for (int i = 0; i < 4; i++) {
        float4 a = a4[lane + 64 * i];
        float4 w = w4[lane + 64 * i];
        s += a.x * w.x + a.y * w.y + a.z * w.z + a.w * w.w;
    }
#pragma unroll
    for (int off = 32; off; off >>= 1) s += __shfl_down(s, off, 64);
    if (lane == 0) {
        float v = s + bp[j];
        h0[b * H_ + j] = v;
        unsigned short h_, l_;
        split_bf16(v, &h_, &l_);
        hhi[b * H_ + j] = h_;
        hlo[b * H_ + j] = l_;
    }
}

// ---------------------------------------------------------------- x prep (SOS)
__global__ __launch_bounds__(256) void k_prep_x0(const float* __restrict__ emb,
    unsigned short* __restrict__ xhi, unsigned short* __restrict__ xlo)
{
    int b = blockIdx.x;
    int tid = threadIdx.x;
    float4 v4 = *(const float4*)(emb + (size_t)SOS_ * H_ + tid * 4);
    ushort4 h, l;
    split_bf16(v4.x, &h.x, &l.x);
    split_bf16(v4.y, &h.y, &l.y);
    split_bf16(v4.z, &h.z, &l.z);
    split_bf16(v4.w, &h.w, &l.w);
    *(ushort4*)(xhi + (size_t)b * H_ + tid * 4) = h;
    *(ushort4*)(xlo + (size_t)b * H_ + tid * 4) = l;
}

// ---------------------------------------------------------------- gates GEMM (MFMA)
// gi = x@Wih^T, gh = h@Whh^T split-K fp32 partials.  Grid 384: jt(48) x half(2) x ks(4).
// K-chunk 256 = 4 iters.  All 4 LDS buffers staged upfront; raw barrier + counted
// vmcnt(12) per iter (no drain).  vmcnt ledger: younger-than-stage(i) = 12 ops, exact.
__global__ __launch_bounds__(256) void k_gates_gemm2(
    const unsigned short* __restrict__ xhi, const unsigned short* __restrict__ xlo,
    const unsigned short* __restrict__ hhi, const unsigned short* __restrict__ hlo,
    const unsigned short* __restrict__ wihh, const unsigned short* __restrict__ wihl,
    const unsigned short* __restrict__ whhh, const unsigned short* __restrict__ whhl,
    float* __restrict__ gbuf)
{
    __shared__ __align__(128) char Bsm[4][16384];  // [buf][hi 8K | lo 8K]
    int tid = threadIdx.x;
    int lane = tid & 63;
    int wv = tid >> 6;
    int blk = blockIdx.x;
    int jt = blk % 48;
    int rest = blk / 48;        // 0..7
    int half = rest & 1;        // 0: ih (A=x), 1: hh (A=h)
    int ks = rest >> 1;         // 0..3 split-K chunk
    int kbase = ks * 256;
    int row0 = jt * 64;

    const unsigned short* Ahi_g = half ? hhi : xhi;
    const unsigned short* Alo_g = half ? hlo : xlo;
    const unsigned short* Bhi_g = half ? whhh : wihh;
    const unsigned short* Blo_g = half ? whhl : wihl;

    // staging geometry: lane -> (tile row, 16B slot); XOR-swizzled global source
    int r0 = wv * 8 + (lane >> 3);
    int r1 = r0 + 32;
    int kslt = (lane & 7) * 16;
    size_t so0 = (size_t)(row0 + r0) * 2048 + (size_t)(kslt ^ ((r0 & 7) << 4));
    size_t so1 = (size_t)(row0 + r1) * 2048 + (size_t)(kslt ^ ((r1 & 7) << 4));

    int mrow = wv * 16 + (lane & 15);
    int koff = (lane >> 4) * 8;             // elements
    int kb = koff * 2;                      // bytes

    f32x4 acc[4];
#pragma unroll
    for (int i = 0; i < 4; i++) acc[i] = (f32x4){0.f, 0.f, 0.f, 0.f};

    auto stage = [&](int BUF, int KC) {
        const char* bh = (const char*)Bhi_g + (size_t)KC * 2;
        const char* bl = (const char*)Blo_g + (size_t)KC * 2;
        char* base = Bsm[BUF] + wv * 1024;  // wave-uniform; HW adds lane*16
        gload_lds16(bh + so0, base);
        gload_lds16(bh + so1, base + 4096);
        gload_lds16(bl + so0, base + 8192);
        gload_lds16(bl + so1, base + 12288);
    };

    stage(0, kbase);
    stage(1, kbase + 64);
    stage(2, kbase + 128);
    stage(3, kbase + 192);

    for (int it = 0; it < 4; ++it) {
        // exact ledger: 12 vmem ops issued after stage(it)'s last load
        asm volatile("s_waitcnt vmcnt(12)" ::: "memory");
        __builtin_amdgcn_s_barrier();
        __builtin_amdgcn_sched_barrier(0);
        int kc = kbase + it * 64;
        const unsigned short* ap = Ahi_g + (size_t)mrow * 1024 + kc + koff;
        const unsigned short* alp = Alo_g + (size_t)mrow * 1024 + kc + koff;
        bf16x8 ah0 = *(const bf16x8*)ap;
        bf16x8 ah1 = *(const bf16x8*)(ap + 32);
        bf16x8 al0 = *(const bf16x8*)alp;
        bf16x8 al1 = *(const bf16x8*)(alp + 32);
        const char* bhp = Bsm[it];
        const char* blp = Bsm[it] + 8192;
#pragma unroll
        for (int tv = 0; tv < 4; tv++) {
            int brow = tv * 16 + (lane & 15);
            int swz = (brow & 7) << 4;
            int ro = brow * 128;
            bf16x8 bh0 = *(const bf16x8*)(bhp + ro + (kb ^ swz));
            bf16x8 bh1 = *(const bf16x8*)(bhp + ro + ((kb + 64) ^ swz));
            bf16x8 bl0 = *(const bf16x8*)(blp + ro + (kb ^ swz));
            bf16x8 bl1 = *(const bf16x8*)(blp + ro + ((kb + 64) ^ swz));
            acc[tv] = __builtin_amdgcn_mfma_f32_16x16x32_bf16(ah0, bh0, acc[tv], 0, 0, 0);
            acc[tv] = __builtin_amdgcn_mfma_f32_16x16x32_bf16(ah1, bh1, acc[tv], 0, 0, 0);
            acc[tv] = __builtin_amdgcn_mfma_f32_16x16x32_bf16(al0, bh0, acc[tv], 0, 0, 0);
            acc[tv] = __builtin_amdgcn_mfma_f32_16x16x32_bf16(al1, bh1, acc[tv], 0, 0, 0);
            acc[tv] = __builtin_amdgcn_mfma_f32_16x16x32_bf16(ah0, bl0, acc[tv], 0, 0, 0);
            acc[tv] = __builtin_amdgcn_mfma_f32_16x16x32_bf16(ah1, bl1, acc[tv], 0, 0, 0);
        }
    }

    // epilogue: C/D layout col = lane&15 (n), row = (lane>>4)*4 + reg (b)
    int col = lane & 15;
    int quad = lane >> 4;
    float* og = gbuf + (size_t)((ks * 2 + half) * 64) * 3072;
#pragma unroll
    for (int tv = 0; tv < 4; tv++) {
#pragma unroll
        for (int r = 0; r < 4; r++) {
            int b = wv * 16 + quad * 4 + r;
            og[(size_t)b * 3072 + jt * 64 + tv * 16 + col] = acc[tv][r];
        }
    }
}

// ---------------------------------------------------------------- gate elementwise
__global__ __launch_bounds__(256) void k_gru_elem2(
    const float* __restrict__ gbuf, const float* __restrict__ bih,
    const float* __restrict__ bhh, const float* __restrict__ hprev,
    float* __restrict__ hnext, unsigned short* __restrict__ hnhi,
    unsigned short* __restrict__ hnlo)
{
    int idx = blockIdx.x * 256 + threadIdx.x;   // 0..65535
    int b = idx >> 10;
    int j = idx & 1023;
    float ir = bih[j], hr = bhh[j];
    float iz = bih[H_ + j], hz = bhh[H_ + j];
    float in_ = bih[2 * H_ + j], hn = bhh[2 * H_ + j];
#pragma unroll
    for (int ks = 0; ks < 4; ks++) {
        const float* gi = gbuf + (size_t)(ks * 2 * 64 + b) * 3072;
        const float* gh = gbuf + (size_t)((ks * 2 + 1) * 64 + b) * 3072;
        ir += gi[j];          hr += gh[j];
        iz += gi[H_ + j];     hz += gh[H_ + j];
        in_ += gi[2 * H_ + j]; hn += gh[2 * H_ + j];
    }
    float r = 1.f / (1.f + expf(-(ir + hr)));
    float z = 1.f / (1.f + expf(-(iz + hz)));
    float n = tanhf(in_ + r * hn);
    float hp = hprev[idx];
    float v = (1.f - z) * n + z * hp;
    hnext[idx] = v;
    unsigned short h_, l_;
    split_bf16(v, &h_, &l_);
    hnhi[idx] = h_;
    hnlo[idx] = l_;
}

// ---------------------------------------------------------------- logits + argmax
// logits = h @ Wout^T + bout.  Block: 64 b x 64 v, K=1024 = 16 iters.
// 4-buffer pipeline, stage 3 ahead; raw barrier + counted vmcnt (8/12/16).
__global__ __launch_bounds__(256) void k_logits_argmax2(
    const unsigned short* __restrict__ hhi, const unsigned short* __restrict__ hlo,
    const unsigned short* __restrict__ wouth, const unsigned short* __restrict__ woutl,
    const float* __restrict__ bout, unsigned long long* __restrict__ partials,
    int nblk)
{
    __shared__ __align__(128) char Bsm[4][16384];
    int tid = threadIdx.x;
    int lane = tid & 63;
    int wv = tid >> 6;
    int row0 = blockIdx.x * 64;   // vbase

    int r0 = wv * 8 + (lane >> 3);
    int r1 = r0 + 32;
    int kslt = (lane & 7) * 16;
    size_t so0 = (size_t)(row0 + r0) * 2048 + (size_t)(kslt ^ ((r0 & 7) << 4));
    size_t so1 = (size_t)(row0 + r1) * 2048 + (size_t)(kslt ^ ((r1 & 7) << 4));

    int mrow = wv * 16 + (lane & 15);
    int koff = (lane >> 4) * 8;
    int kb = koff * 2;

    f32x4 acc[4];
#pragma unroll
    for (int i = 0; i < 4; i++) acc[i] = (f32x4){0.f, 0.f, 0.f, 0.f};

    auto stage = [&](int BUF, int KC) {
        const char* bh = (const char*)wouth + (size_t)KC * 2;
        const char* bl = (const char*)woutl + (size_t)KC * 2;
        char* base = Bsm[BUF] + wv * 1024;
        gload_lds16(bh + so0, base);
        gload_lds16(bh + so1, base + 4096);
        gload_lds16(bl + so0, base + 8192);
        gload_lds16(bl + so1, base + 12288);
    };

    stage(0, 0);
    stage(1, 64);
    stage(2, 128);

    for (int it = 0; it < 16; ++it) {
        // vmcnt ledger (ops younger than stage(it)'s last load):
        //   it=0: st1,st2 = 8;  it=1: st2,A0,st3 = 12;  it>=2: A(i-2),st(i+1),A(i-1),st(i+2) = 16
        if (it == 0)      asm volatile("s_waitcnt vmcnt(8)"  ::: "memory");
        else if (it == 1) asm volatile("s_waitcnt vmcnt(12)" ::: "memory");
        else              asm volatile("s_waitcnt vmcnt(16)" ::: "memory");
        __builtin_amdgcn_s_barrier();
        __builtin_amdgcn_sched_barrier(0);
        int kc = it * 64;
        const unsigned short* ap = hhi + (size_t)mrow * 1024 + kc + koff;
        const unsigned short* alp = hlo + (size_t)mrow * 1024 + kc + koff;
        bf16x8 ah0 = *(const bf16x8*)ap;
        bf16x8 ah1 = *(const bf16x8*)(ap + 32);
        bf16x8 al0 = *(const bf16x8*)alp;
        bf16x8 al1 = *(const bf16x8*)(alp + 32);
        const char* bhp = Bsm[it & 3];
        const char* blp = Bsm[it & 3] + 8192;
#pragma unroll
        for (int tv = 0; tv < 4; tv++) {
            int brow = tv * 16 + (lane & 15);
            int swz = (brow & 7) << 4;
            int ro = brow * 128;
            bf16x8 bh0 = *(const bf16x8*)(bhp + ro + (kb ^ swz));
            bf16x8 bh1 = *(const bf16x8*)(bhp + ro + ((kb + 64) ^ swz));
            bf16x8 bl0 = *(const bf16x8*)(blp + ro + (kb ^ swz));
            bf16x8 bl1 = *(const bf16x8*)(blp + ro + ((kb + 64) ^ swz));
            acc[tv] = __builtin_amdgcn_mfma_f32_16x16x32_bf16(ah0, bh0, acc[tv], 0, 0, 0);
            acc[tv] = __builtin_amdgcn_mfma_f32_16x16x32_bf16(ah1, bh1, acc[tv], 0, 0, 0);
            acc[tv] = __builtin_amdgcn_mfma_f32_16x16x32_bf16(al0, bh0, acc[tv], 0, 0, 0);
            acc[tv] = __builtin_amdgcn_mfma_f32_16x16x32_bf16(al1, bh1, acc[tv], 0, 0, 0);
            acc[tv] = __builtin_amdgcn_mfma_f32_16x16x32_bf16(ah0, bl0, acc[tv], 0, 0, 0);
            acc[tv] = __builtin_amdgcn_mfma_f32_16x16x32_bf16(ah1, bl1, acc[tv], 0, 0, 0);
        }
        // prefetch 3 ahead into buf[(it+3)&3] (WAR-safe: its readers finished
        // before this iter's barrier)
        if (it <= 12) stage((it + 3) & 3, (it + 3) * 64);
    }

    // epilogue: argmax keys.  C/D layout col = lane&15 (v), row = (lane>>4)*4 + reg (b)
    int col = lane & 15;
    int quad = lane >> 4;
    unsigned long long kmax[4] = {0ull, 0ull, 0ull, 0ull};
#pragma unroll
    for (int tv = 0; tv < 4; tv++) {
        int v = row0 + tv * 16 + col;
        float bo = bout[v];
#pragma unroll
        for (int r = 0; r < 4; r++) {
            float lg = acc[tv][r] + bo;
            unsigned long long key = ((unsigned long long)ord_of_float(lg) << 32)
                                   | (unsigned long long)(0x7FFFFFFFu - (uint32_t)v);
            if (key > kmax[r]) kmax[r] = key;
        }
    }
#pragma unroll
    for (int r = 0; r < 4; r++) {
        unsigned long long k = kmax[r];
#pragma unroll
        for (int off = 1; off < 16; off <<= 1) {
            unsigned long long o = shfl_xor_u64(k, off);
            if (o > k) k = o;
        }
        kmax[r] = k;
    }
    if (col == 0) {
#pragma unroll
        for (int r = 0; r < 4; r++) {
            int b = wv * 16 + quad * 4 + r;
            partials[(size_t)b * nblk + blockIdx.x] = kmax[r];
        }
    }
}

// ---------------------------------------------------------------- token reduce + next-x prep
__global__ __launch_bounds__(256) void k_token2(
    const unsigned long long* __restrict__ partials, int nblk,
    int* __restrict__ tok, float* __restrict__ out_tokens, int t,
    const float* __restrict__ emb,
    unsigned short* __restrict__ xhi, unsigned short* __restrict__ xlo)
{
    __shared__ int s_tok;
    int b = blockIdx.x;
    int tid = threadIdx.x;
    if (tid < 64) {
        unsigned long long k = 0ull;
        for (int i = tid; i < nblk; i += 64) {
            unsigned long long p = partials[(size_t)b * nblk + i];
            if (p > k) k = p;
        }
#pragma unroll
        for (int off = 32; off; off >>= 1) {
            unsigned long long o = shfl_xor_u64(k, off);
            if (o > k) k = o;
        }
        if (tid == 0) {
            int v = (int)(0x7FFFFFFFu - (uint32_t)(k & 0xFFFFFFFFull));
            tok[b] = v;
            out_tokens[b * T_ + t] = (float)v;
            s_tok = v;
        }
    }
    __syncthreads();
    int row = s_tok;
    float4 v4 = *(const float4*)(emb + (size_t)row * H_ + tid * 4);
    ushort4 h, l;
    split_bf16(v4.x, &h.x, &l.x);
    split_bf16(v4.y, &h.y, &l.y);
    split_bf16(v4.z, &h.z, &l.z);
    split_bf16(v4.w, &h.w, &l.w);
    *(ushort4*)(xhi + (size_t)b * H_ + tid * 4) = h;
    *(ushort4*)(xlo + (size_t)b * H_ + tid * 4) = l;
}

// ---------------------------------------------------------------- final h copy
__global__ __launch_bounds__(256) void k_copy_h(const float* __restrict__ h,
                                               float* __restrict__ out)
{
    int i = (blockIdx.x * 256 + threadIdx.x) * 4;
    *(float4*)(out + i) = *(const float4*)(h + i);
}

// ---------------------------------------------------------------- launch
extern "C" void kernel_launch(void* const* d_in, const int* in_sizes, int n_in,
                              void* d_out, int out_size, void* d_ws, size_t ws_size,
                              hipStream_t stream)
{
    const float* latent = (const float*)d_in[0];
    const float* Wp     = (const float*)d_in[1];
    const float* bp     = (const float*)d_in[2];
    const float* emb    = (const float*)d_in[3];
    const float* Wih    = (const float*)d_in[4];
    const float* bih    = (const float*)d_in[5];
    const float* Whh    = (const float*)d_in[6];
    const float* bhh    = (const float*)d_in[7];
    const float* Wout   = (const float*)d_in[8];
    const float* bout   = (const float*)d_in[9];
    float* out = (float*)d_out;

    char* ws = (char*)d_ws;
    // ---- workspace layout ----
    float* h0   = (float*)(ws + 0);             // 256 KiB
    float* h1   = (float*)(ws + 262144);        // 256 KiB
    int* tok    = (int*)(ws + 524288);          // 1 KiB
    unsigned long long* partials = (unsigned long long*)(ws + 525312);  // 256 KiB
    float* gbuf = (float*)(ws + 787456);        // 8*64*3072*4 = 6 MiB
    unsigned short* hhi0 = (unsigned short*)(ws + 7078912);   // 128 KiB each
    unsigned short* hlo0 = (unsigned short*)(ws + 7209984);
    unsigned short* hhi1 = (unsigned short*)(ws + 7341056);
    unsigned short* hlo1 = (unsigned short*)(ws + 7472128);
    unsigned short* xhi  = (unsigned short*)(ws + 7603200);
    unsigned short* xlo  = (unsigned short*)(ws + 7734272);
    unsigned short* wihh = (unsigned short*)(ws + 7865344);   // 6 MiB each
    unsigned short* wihl = (unsigned short*)(ws + 14156800);
    unsigned short* whhh = (unsigned short*)(ws + 20448256);
    unsigned short* whhl = (unsigned short*)(ws + 26739712);
    unsigned short* wouth = (unsigned short*)(ws + 33031168); // 62.5 MiB each
    unsigned short* woutl = (unsigned short*)(ws + 98567168); // end ~156.5 MiB

    const int NBLK = V_ / 64;   // 500

    // one-time weight splits (amortized over 20 steps)
    k_split_w<<<3072, 256, 0, stream>>>(Wih, wihh, wihl, 3 * H_ * H_ / 4);
    k_split_w<<<3072, 256, 0, stream>>>(Whh, whhh, whhl, 3 * H_ * H_ / 4);
    k_split_w<<<32000, 256, 0, stream>>>(Wout, wouth, woutl, V_ * H_ / 4);

    k_init_hidden<<<16384, 256, 0, stream>>>(latent, Wp, bp, h0, hhi0, hlo0);
    k_prep_x0<<<64, 256, 0, stream>>>(emb, xhi, xlo);

    float* hp = h0;  unsigned short* hphi = hhi0;  unsigned short* hplo = hlo0;
    float* hn = h1;  unsigned short* hnhi = hhi1;  unsigned short* hnlo = hlo1;
    for (int t = 0; t < T_; t++) {
        k_gates_gemm2<<<384, 256, 0, stream>>>(xhi, xlo, hphi, hplo,
                                               wihh, wihl, whhh, whhl, gbuf);
        k_gru_elem2<<<256, 256, 0, stream>>>(gbuf, bih, bhh, hp, hn, hnhi, hnlo);
        k_logits_argmax2<<<NBLK, 256, 0, stream>>>(hnhi, hnlo, wouth, woutl,
                                                   bout, partials, NBLK);
        k_token2<<<B_, 256, 0, stream>>>(partials, NBLK, tok, out, t, emb, xhi, xlo);
        { float* tf = hp; hp = hn; hn = tf; }
        { unsigned short* ts = hphi; hphi = hnhi; hnhi = ts; }
        { unsigned short* ts = hplo; hplo = hnlo; hnlo = ts; }
    }
    k_copy_h<<<64, 256, 0, stream>>>(hp, out + B_ * T_);
}